// Round 1
// baseline (122.093 us; speedup 1.0000x reference)
//
#include <hip/hip_runtime.h>
#include <hip/hip_bf16.h>

// segment_prod over sorted batch indices.
// feats: [N_NODES, 64] fp32   batch: [N_NODES] int32 (sorted ascending)
// out:   [NUM_SEGMENTS, 64] fp32, empty segments = 1.0
//
// One block per segment. Binary-search [start,end) in batch, then stream
// contiguous rows with float4 loads: thread t handles quad (t&15) of row
// (start + t>>4 + k*16). LDS tree-reduce the 16 row-groups per quad.

__global__ __launch_bounds__(256) void PoolProd_kernel(
    const float4* __restrict__ feats,   // [N, 16] float4 view of [N, 64] fp32
    const int*    __restrict__ batch,   // [N]
    float4*       __restrict__ out,     // [S, 16]
    int n_nodes)
{
    const int s = blockIdx.x;

    // lower_bound(batch, s)
    int lo = 0, hi = n_nodes;
    while (lo < hi) {
        int mid = (lo + hi) >> 1;
        if (batch[mid] < s) lo = mid + 1; else hi = mid;
    }
    const int start = lo;

    // lower_bound(batch, s+1)
    hi = n_nodes;
    while (lo < hi) {
        int mid = (lo + hi) >> 1;
        if (batch[mid] < s + 1) lo = mid + 1; else hi = mid;
    }
    const int end = lo;

    const int tid  = threadIdx.x;
    const int quad = tid & 15;   // which float4 within the 64-float row
    const int rofs = tid >> 4;   // row offset within a 16-row group

    float4 acc = make_float4(1.0f, 1.0f, 1.0f, 1.0f);
    for (int r = start + rofs; r < end; r += 16) {
        float4 v = feats[(size_t)r * 16 + quad];
        acc.x *= v.x; acc.y *= v.y; acc.z *= v.z; acc.w *= v.w;
    }

    __shared__ float4 lds[256];
    lds[tid] = acc;
    __syncthreads();

    #pragma unroll
    for (int step = 128; step >= 16; step >>= 1) {
        if (tid < step) {
            float4 o = lds[tid + step];
            float4 m = lds[tid];
            m.x *= o.x; m.y *= o.y; m.z *= o.z; m.w *= o.w;
            lds[tid] = m;
        }
        __syncthreads();
    }

    if (tid < 16) {
        out[(size_t)s * 16 + tid] = lds[tid];
    }
}

extern "C" void kernel_launch(void* const* d_in, const int* in_sizes, int n_in,
                              void* d_out, int out_size, void* d_ws, size_t ws_size,
                              hipStream_t stream) {
    const float4* feats = (const float4*)d_in[0];
    const int*    batch = (const int*)d_in[1];
    float4*       out   = (float4*)d_out;

    const int n_nodes      = in_sizes[0] / 64;   // 2,000,000
    const int num_segments = out_size   / 64;    // 8192

    PoolProd_kernel<<<num_segments, 256, 0, stream>>>(feats, batch, out, n_nodes);
}

// Round 2
// 103.573 us; speedup vs baseline: 1.1788x; 1.1788x over previous
//
#include <hip/hip_runtime.h>
#include <hip/hip_bf16.h>

// segment_prod over sorted batch indices, two-phase:
//   Phase 1: bounds_kernel — thread s computes lower_bound(batch, s) into
//            seg_start[s] (s = 0..NUM_SEGMENTS; seg_start[S] = n_nodes).
//            All searches run in parallel -> latency chains pipeline.
//   Phase 2: prod_kernel — one block per segment, reads [start,end) with two
//            broadcast loads, streams contiguous rows with float4 loads,
//            LDS tree-reduce. Empty segments -> 1.0.

__global__ __launch_bounds__(256) void bounds_kernel(
    const int* __restrict__ batch,  // [N] sorted
    int*       __restrict__ seg_start,
    int n_nodes, int num_segments)
{
    const int s = blockIdx.x * blockDim.x + threadIdx.x;
    if (s > num_segments) return;
    if (s == num_segments) { seg_start[s] = n_nodes; return; }
    if (s == 0)            { seg_start[0] = 0;       return; }

    int lo = 0, hi = n_nodes;
    while (lo < hi) {
        int mid = (lo + hi) >> 1;
        if (batch[mid] < s) lo = mid + 1; else hi = mid;
    }
    seg_start[s] = lo;
}

__global__ __launch_bounds__(256) void prod_kernel(
    const float4* __restrict__ feats,     // [N, 16] float4 view of [N, 64] fp32
    const int*    __restrict__ seg_start, // [S+1]
    float4*       __restrict__ out)       // [S, 16]
{
    const int s     = blockIdx.x;
    const int start = seg_start[s];
    const int end   = seg_start[s + 1];

    const int tid  = threadIdx.x;
    const int quad = tid & 15;   // float4 index within the 64-float row
    const int rofs = tid >> 4;   // row offset within a 16-row group

    float4 acc = make_float4(1.0f, 1.0f, 1.0f, 1.0f);
    for (int r = start + rofs; r < end; r += 16) {
        float4 v = feats[(size_t)r * 16 + quad];
        acc.x *= v.x; acc.y *= v.y; acc.z *= v.z; acc.w *= v.w;
    }

    __shared__ float4 lds[256];
    lds[tid] = acc;
    __syncthreads();

    #pragma unroll
    for (int step = 128; step >= 16; step >>= 1) {
        if (tid < step) {
            float4 o = lds[tid + step];
            float4 m = lds[tid];
            m.x *= o.x; m.y *= o.y; m.z *= o.z; m.w *= o.w;
            lds[tid] = m;
        }
        __syncthreads();
    }

    if (tid < 16) {
        out[(size_t)s * 16 + tid] = lds[tid];
    }
}

extern "C" void kernel_launch(void* const* d_in, const int* in_sizes, int n_in,
                              void* d_out, int out_size, void* d_ws, size_t ws_size,
                              hipStream_t stream) {
    const float4* feats = (const float4*)d_in[0];
    const int*    batch = (const int*)d_in[1];
    float4*       out   = (float4*)d_out;
    int*          seg_start = (int*)d_ws;   // (S+1) ints

    const int n_nodes      = in_sizes[0] / 64;   // 2,000,000
    const int num_segments = out_size   / 64;    // 8192

    const int nb = (num_segments + 1 + 255) / 256;
    bounds_kernel<<<nb, 256, 0, stream>>>(batch, seg_start, n_nodes, num_segments);
    prod_kernel<<<num_segments, 256, 0, stream>>>(feats, seg_start, out);
}

// Round 3
// 94.265 us; speedup vs baseline: 1.2952x; 1.0987x over previous
//
#include <hip/hip_runtime.h>
#include <hip/hip_bf16.h>

// segment_prod over sorted batch indices, two-phase:
//   Phase 1: bounds_scan_kernel — linear boundary scan (BW-bound, ~2 us):
//            thread i compares batch[i] vs batch[i+1]; on a jump writes
//            seg_start[s] = i+1 for all s in (batch[i], batch[i+1]].
//            Thread 0 additionally fills [0, batch[0]] with 0.
//            Covers every s in [0, NUM_SEGMENTS] exactly once -> deterministic.
//   Phase 2: prod_kernel — one WAVE per segment. Lane layout: quad = lane&15
//            (float4 within 64-float row), rofs = lane>>4 (row stride 4).
//            2-deep unrolled nontemporal float4 stream, shuffle-reduce over
//            lane bits 4,5. Empty segments -> 1.0.

typedef float f32x4 __attribute__((ext_vector_type(4)));

__global__ __launch_bounds__(256) void bounds_scan_kernel(
    const int* __restrict__ batch,      // [N] sorted
    int*       __restrict__ seg_start,  // [S+1]
    int n_nodes, int num_segments)
{
    const int i = blockIdx.x * blockDim.x + threadIdx.x;
    if (i >= n_nodes) return;
    const int b0 = batch[i];
    const int b1 = (i + 1 < n_nodes) ? batch[i + 1] : num_segments;
    if (i == 0) {
        for (int s = 0; s <= b0; ++s) seg_start[s] = 0;
    }
    for (int s = b0 + 1; s <= b1; ++s) seg_start[s] = i + 1;
}

__global__ __launch_bounds__(256) void prod_kernel(
    const f32x4* __restrict__ feats,     // [N, 16] float4 view of [N, 64] fp32
    const int*   __restrict__ seg_start, // [S+1]
    f32x4*       __restrict__ out)       // [S, 16]
{
    const int gtid = blockIdx.x * 256 + threadIdx.x;
    const int s    = gtid >> 6;          // one wave per segment
    const int lane = gtid & 63;
    const int quad = lane & 15;          // float4 index within row
    const int rofs = lane >> 4;          // 0..3, row stride 4

    const int start = seg_start[s];
    const int end   = seg_start[s + 1];

    f32x4 a0 = {1.f, 1.f, 1.f, 1.f};
    f32x4 a1 = {1.f, 1.f, 1.f, 1.f};

    int r = start + rofs;
    for (; r + 4 < end; r += 8) {
        f32x4 v0 = __builtin_nontemporal_load(&feats[(size_t)r       * 16 + quad]);
        f32x4 v1 = __builtin_nontemporal_load(&feats[(size_t)(r + 4) * 16 + quad]);
        a0 *= v0;
        a1 *= v1;
    }
    if (r < end) {
        a0 *= __builtin_nontemporal_load(&feats[(size_t)r * 16 + quad]);
    }
    a0 *= a1;

    // reduce the 4 row-groups: lanes differing in bits 4 and 5 hold same quad
    f32x4 t;
    t.x = __shfl_xor(a0.x, 16); t.y = __shfl_xor(a0.y, 16);
    t.z = __shfl_xor(a0.z, 16); t.w = __shfl_xor(a0.w, 16);
    a0 *= t;
    t.x = __shfl_xor(a0.x, 32); t.y = __shfl_xor(a0.y, 32);
    t.z = __shfl_xor(a0.z, 32); t.w = __shfl_xor(a0.w, 32);
    a0 *= t;

    if (lane < 16) {
        out[(size_t)s * 16 + quad] = a0;
    }
}

extern "C" void kernel_launch(void* const* d_in, const int* in_sizes, int n_in,
                              void* d_out, int out_size, void* d_ws, size_t ws_size,
                              hipStream_t stream) {
    const f32x4* feats = (const f32x4*)d_in[0];
    const int*   batch = (const int*)d_in[1];
    f32x4*       out   = (f32x4*)d_out;
    int*         seg_start = (int*)d_ws;   // (S+1) ints

    const int n_nodes      = in_sizes[0] / 64;   // 2,000,000
    const int num_segments = out_size   / 64;    // 8192

    const int nb_scan = (n_nodes + 255) / 256;
    bounds_scan_kernel<<<nb_scan, 256, 0, stream>>>(batch, seg_start, n_nodes, num_segments);

    const int nb_prod = (num_segments * 64) / 256;  // one wave per segment
    prod_kernel<<<nb_prod, 256, 0, stream>>>(feats, seg_start, out);
}

// Round 4
// 87.985 us; speedup vs baseline: 1.3876x; 1.0714x over previous
//
#include <hip/hip_runtime.h>
#include <hip/hip_bf16.h>

// segment_prod over sorted batch indices, two-phase:
//   Phase 1: bounds_scan_kernel — linear boundary scan (BW-bound, ~2 us).
//   Phase 2: prod_kernel — one WAVE per segment (8192 waves = exactly full
//            residency on 256 CUs). Lane layout: quad = lane&15 (float4
//            within 64-float row), rofs = lane>>4 (row stride 4).
//            4-deep unrolled nontemporal float4 stream (4 independent
//            accumulators -> 4 loads in flight per lane), shuffle-reduce
//            over lane bits 4,5. Empty segments -> 1.0.

typedef float f32x4 __attribute__((ext_vector_type(4)));

__global__ __launch_bounds__(256) void bounds_scan_kernel(
    const int* __restrict__ batch,      // [N] sorted
    int*       __restrict__ seg_start,  // [S+1]
    int n_nodes, int num_segments)
{
    const int i = blockIdx.x * blockDim.x + threadIdx.x;
    if (i >= n_nodes) return;
    const int b0 = batch[i];
    const int b1 = (i + 1 < n_nodes) ? batch[i + 1] : num_segments;
    if (i == 0) {
        for (int s = 0; s <= b0; ++s) seg_start[s] = 0;
    }
    for (int s = b0 + 1; s <= b1; ++s) seg_start[s] = i + 1;
}

__global__ __launch_bounds__(256) void prod_kernel(
    const f32x4* __restrict__ feats,     // [N, 16] float4 view of [N, 64] fp32
    const int*   __restrict__ seg_start, // [S+1]
    f32x4*       __restrict__ out)       // [S, 16]
{
    const int gtid = blockIdx.x * 256 + threadIdx.x;
    const int s    = gtid >> 6;          // one wave per segment
    const int lane = gtid & 63;
    const int quad = lane & 15;          // float4 index within row
    const int rofs = lane >> 4;          // 0..3, row stride 4

    const int start = seg_start[s];
    const int end   = seg_start[s + 1];

    f32x4 a0 = {1.f, 1.f, 1.f, 1.f};
    f32x4 a1 = {1.f, 1.f, 1.f, 1.f};
    f32x4 a2 = {1.f, 1.f, 1.f, 1.f};
    f32x4 a3 = {1.f, 1.f, 1.f, 1.f};

    int r = start + rofs;
    // main loop: 16 rows per iteration (4 rofs-groups x unroll 4)
    for (; r + 12 < end; r += 16) {
        f32x4 v0 = __builtin_nontemporal_load(&feats[(size_t)(r     ) * 16 + quad]);
        f32x4 v1 = __builtin_nontemporal_load(&feats[(size_t)(r +  4) * 16 + quad]);
        f32x4 v2 = __builtin_nontemporal_load(&feats[(size_t)(r +  8) * 16 + quad]);
        f32x4 v3 = __builtin_nontemporal_load(&feats[(size_t)(r + 12) * 16 + quad]);
        a0 *= v0;
        a1 *= v1;
        a2 *= v2;
        a3 *= v3;
    }
    // tail: at most 3 steps of 4 rows
    for (; r < end; r += 4) {
        a0 *= __builtin_nontemporal_load(&feats[(size_t)r * 16 + quad]);
    }
    a0 *= a1;
    a2 *= a3;
    a0 *= a2;

    // reduce the 4 row-groups: lanes differing in bits 4 and 5 hold same quad
    f32x4 t;
    t.x = __shfl_xor(a0.x, 16); t.y = __shfl_xor(a0.y, 16);
    t.z = __shfl_xor(a0.z, 16); t.w = __shfl_xor(a0.w, 16);
    a0 *= t;
    t.x = __shfl_xor(a0.x, 32); t.y = __shfl_xor(a0.y, 32);
    t.z = __shfl_xor(a0.z, 32); t.w = __shfl_xor(a0.w, 32);
    a0 *= t;

    if (lane < 16) {
        out[(size_t)s * 16 + quad] = a0;
    }
}

extern "C" void kernel_launch(void* const* d_in, const int* in_sizes, int n_in,
                              void* d_out, int out_size, void* d_ws, size_t ws_size,
                              hipStream_t stream) {
    const f32x4* feats = (const f32x4*)d_in[0];
    const int*   batch = (const int*)d_in[1];
    f32x4*       out   = (f32x4*)d_out;
    int*         seg_start = (int*)d_ws;   // (S+1) ints

    const int n_nodes      = in_sizes[0] / 64;   // 2,000,000
    const int num_segments = out_size   / 64;    // 8192

    const int nb_scan = (n_nodes + 255) / 256;
    bounds_scan_kernel<<<nb_scan, 256, 0, stream>>>(batch, seg_start, n_nodes, num_segments);

    const int nb_prod = (num_segments * 64) / 256;  // one wave per segment
    prod_kernel<<<nb_prod, 256, 0, stream>>>(feats, seg_start, out);
}